// Round 17
// baseline (23.246 us; speedup 1.0000x reference)
//
#include <hip/hip_runtime.h>

typedef __attribute__((ext_vector_type(8)))  short short8;
typedef __attribute__((ext_vector_type(16))) float f32x16;

#define BATCH  8
#define NPTS   4096
#define HALF_T 2048           // targets per block (2-way target split)
#define TPB    512            // 8 waves; each wave owns 64 query columns
#define ONEB   0x3F80u        // bf16(1.0)
#define BIASB  0x4080u        // bf16(4.0)
#define BIASF  4.0f
#define NQTOT  (2 * BATCH * NPTS)   // 65536 (dir-major query count)

// round-to-nearest-even f32 -> bf16 bits
__device__ __forceinline__ unsigned bfr(float f) {
    unsigned u = __float_as_uint(f);
    return (u + 0x7FFFu + ((u >> 16) & 1u)) >> 16;
}
__device__ __forceinline__ float ubf(unsigned s) {
    return __uint_as_float(s << 16);
}

// MFMA chamfer, round-17: each wave owns 64 queries (TWO B-frags), so one
// ds_read_b128 of an A-tile feeds TWO mfma_32x32x16_bf16 — per-CU ds_read
// halves (1024 -> 512) while MFMA/min3 totals stay constant. Block = 512
// queries x 2048 targets (target half th); partial col-mins go to part[]
// with plain coalesced stores; a tiny stage-2 kernel min-combines the two
// halves and reduces. Encoding unchanged (verified absmax 0.0 since r14):
// P = |t-q|^2 + BIAS via K=16 rank factorization, hi k0-7 (lanes<32),
// lo k8-15 (lanes>=32).
__global__ __launch_bounds__(TPB) void chamfer_mfma(
    const float* __restrict__ preds,
    const float* __restrict__ gts,
    float* __restrict__ part)    // [2 th][65536 queries]
{
    const int blk = blockIdx.x;
    const int th  = blk & 1;          // target half
    const int qg  = (blk >> 1) & 7;   // query group (512 queries)
    const int db  = blk >> 4;         // dir*8 + b
    const int dir = db >> 3;
    const int b   = db & 7;

    const float* Q = dir ? gts   : preds;   // query set (output-indexed)
    const float* T = dir ? preds : gts;     // target set (min'd over)

    __shared__ uint4 sA[2 * HALF_T];  // [half][row] A-frags, 64 KiB

    const size_t bbase = (size_t)b * NPTS;
    const int lane = threadIdx.x & 63;
    const int wid  = threadIdx.x >> 6;   // 0..7
    const int la   = lane & 31;
    const int h    = lane >> 5;          // 0: k0-7 (hi), 1: k8-15 (lo)

    // ---- stage this block's 2048 target rows as A-frags (4 rows/thread)
    for (int j = 0; j < 4; ++j) {
        const int r = threadIdx.x + j * TPB;
        const float* tp = T + (bbase + th * HALF_T + r) * 3;
        const float X = tp[0], Y = tp[1], Z = tp[2];
        const float px = -2.f * X, py = -2.f * Y, pz = -2.f * Z;
        const float rt = fmaf(X, X, fmaf(Y, Y, Z * Z));
        const unsigned pxh = bfr(px), pyh = bfr(py), pzh = bfr(pz);
        const unsigned pxl = bfr(px - ubf(pxh)), pyl = bfr(py - ubf(pyh)),
                       pzl = bfr(pz - ubf(pzh));
        const unsigned rth = bfr(rt), rtl = bfr(rt - ubf(rth));
        sA[r]          = make_uint4(pxh | (pyh << 16), pzh | (rth << 16),
                                    rtl | (ONEB << 16), ONEB | (ONEB << 16));
        sA[HALF_T + r] = make_uint4(pxl | (pyl << 16), pzl | (pxh << 16),
                                    pyh | (pzh << 16), 0u);
    }

    // ---- this lane's TWO B-frags: queries c0 and c0+32, half h
    const int c0 = qg * 512 + wid * 64 + la;
    short8 bfA, bfB;
    #pragma unroll
    for (int f = 0; f < 2; ++f) {
        const float* qp = Q + (bbase + c0 + f * 32) * 3;
        const float X = qp[0], Y = qp[1], Z = qp[2];
        const float rq = fmaf(X, X, fmaf(Y, Y, Z * Z));
        const unsigned xh = bfr(X), yh = bfr(Y), zh = bfr(Z);
        const unsigned xl = bfr(X - ubf(xh)), yl = bfr(Y - ubf(yh)),
                       zl = bfr(Z - ubf(zh));
        const unsigned rqh = bfr(rq), rql = bfr(rq - ubf(rqh));
        const uint4 b1 = make_uint4(xh | (yh << 16), zh | (ONEB << 16),
                                    ONEB | (rqh << 16), rql | (BIASB << 16));
        const uint4 b2 = make_uint4(xh | (yh << 16), zh | (xl << 16),
                                    yl | (zl << 16), 0u);
        const short8 bf = __builtin_bit_cast(short8, h ? b2 : b1);
        if (f == 0) bfA = bf; else bfB = bf;
    }

    __syncthreads();

    // ---- main loop: 64 tiles, 2 per iter; each A-read feeds 2 MFMAs
    const f32x16 zacc = {};
    f32x16 maccA, maccB;
    #pragma unroll
    for (int i = 0; i < 16; ++i) { maccA[i] = 3.4e38f; maccB[i] = 3.4e38f; }

    const uint4* aBase = sA + h * HALF_T + la;
    for (int t = 0; t < HALF_T / 32; t += 2) {
        const uint4 A0 = aBase[t * 32];
        const uint4 A1 = aBase[t * 32 + 32];
        const f32x16 p0a = __builtin_amdgcn_mfma_f32_32x32x16_bf16(
            __builtin_bit_cast(short8, A0), bfA, zacc, 0, 0, 0);
        const f32x16 p1a = __builtin_amdgcn_mfma_f32_32x32x16_bf16(
            __builtin_bit_cast(short8, A1), bfA, zacc, 0, 0, 0);
        #pragma unroll
        for (int i = 0; i < 16; ++i)
            maccA[i] = fminf(fminf(p0a[i], p1a[i]), maccA[i]);  // v_min3_f32
        const f32x16 p0b = __builtin_amdgcn_mfma_f32_32x32x16_bf16(
            __builtin_bit_cast(short8, A0), bfB, zacc, 0, 0, 0);
        const f32x16 p1b = __builtin_amdgcn_mfma_f32_32x32x16_bf16(
            __builtin_bit_cast(short8, A1), bfB, zacc, 0, 0, 0);
        #pragma unroll
        for (int i = 0; i < 16; ++i)
            maccB[i] = fminf(fminf(p0b[i], p1b[i]), maccB[i]);
    }

    // ---- epilogue per frag: min over 16 row-slots, fold lane halves, store
    #define COLMIN(macc, mout) { \
        const float g0 = fminf(fminf(macc[0],  macc[1]),  macc[2]); \
        const float g1 = fminf(fminf(macc[3],  macc[4]),  macc[5]); \
        const float g2 = fminf(fminf(macc[6],  macc[7]),  macc[8]); \
        const float g3 = fminf(fminf(macc[9],  macc[10]), macc[11]); \
        const float g4 = fminf(fminf(macc[12], macc[13]), macc[14]); \
        mout = fminf(fminf(fminf(g0, g1), fminf(g2, g3)), \
                     fminf(g4, macc[15])); \
        mout = fminf(mout, __shfl_xor(mout, 32, 64)); }

    float mA, mB;
    COLMIN(maccA, mA)
    COLMIN(maccB, mB)
    #undef COLMIN

    if (lane < 32) {
        float* dst = part + (size_t)th * NQTOT + (size_t)db * NPTS + c0;
        dst[0]  = mA;     // query c0
        dst[32] = mB;     // query c0+32
    }
}

// Stage 2: one thread per query; min of the 2 target-half partials,
// subtract BIAS, block-reduce, one atomicAdd per block.
#define TPB2 256
__global__ __launch_bounds__(TPB2) void chamfer_stage2(
    const float* __restrict__ part,
    float* __restrict__ out)
{
    const int g = blockIdx.x * TPB2 + threadIdx.x;   // [0, 65536)

    float s = fminf(part[g], part[NQTOT + g]) - BIASF;

    #pragma unroll
    for (int off = 32; off > 0; off >>= 1)
        s += __shfl_down(s, off, 64);

    __shared__ float red[TPB2 / 64];
    const int lane = threadIdx.x & 63;
    const int wid  = threadIdx.x >> 6;
    if (lane == 0) red[wid] = s;
    __syncthreads();
    if (threadIdx.x == 0) {
        float t = 0.0f;
        #pragma unroll
        for (int w = 0; w < TPB2 / 64; ++w) t += red[w];
        atomicAdd(out, t);
    }
}

extern "C" void kernel_launch(void* const* d_in, const int* in_sizes, int n_in,
                              void* d_out, int out_size, void* d_ws, size_t ws_size,
                              hipStream_t stream) {
    const float* preds = (const float*)d_in[0];
    const float* gts   = (const float*)d_in[1];
    float* out  = (float*)d_out;
    float* part = (float*)d_ws;   // 2 x 65536 floats = 512 KiB

    hipMemsetAsync(out, 0, sizeof(float), stream);
    chamfer_mfma<<<dim3(2 * BATCH * 8 * 2), TPB, 0, stream>>>(preds, gts, part);
    chamfer_stage2<<<dim3(NQTOT / TPB2), TPB2, 0, stream>>>(part, out);
}